// Round 25
// baseline (117.266 us; speedup 1.0000x reference)
//
#include <hip/hip_runtime.h>
#include <hip/hip_bf16.h>
#include <math.h>

#define HDIM 100
#define NFACT 262144
#define FPB   128             // facts per tile (8 waves x 16)
#define NBLK_T 2048           // tiles total
#define TPB   4               // tiles per block (manually unrolled, ping-pong)
#define GRID  (NBLK_T / TPB)  // 512 blocks
#define NTHREADS 512

// K packed to 224: k in [0,112) -> |f - oc| (valid k<100), k in [112,224) -> |f - m|
// (valid k-112<100). Dead k ranges have W1-frag == 0 and z == 0. 112 % 8 == 0 so no
// 8-element MFMA k-group straddles the boundary.
#define KHALF 112
#define NJT 7                 // j-tiles of 16 (112 >= 100)
#define NKC 7                 // k-chunks of 32 (224)
#define NBFRAG (NJT * NKC * 64)   // 3136 uint4 = 50176 B

#define NCOPY 116             // accumulator stripe: pool[112] + S at [112]
#define NSTRIPE 4             // 32 stripes thrashed L2 lines (R12: 49 MB writes)

using short8 = __attribute__((ext_vector_type(8))) short;
using f32x4  = __attribute__((ext_vector_type(4))) float;

// ---------------- ws float-offset layout ----------------
#define WS_B      0               // 12544 floats (3136 uint4 W1-fragments, bf16 bits)
#define WS_ACC    12544           // NSTRIPE stripes x 116 floats (zeroed by k_prep_b)
#define WS_TICKET (WS_ACC + NSTRIPE * NCOPY)   // 1 uint ticket (zeroed by k_prep_b)

__device__ __forceinline__ unsigned short f2bf(float x) {
    unsigned u = __builtin_bit_cast(unsigned, x);
    u += 0x7FFFu + ((u >> 16) & 1u);          // RNE round to bf16
    return (unsigned short)(u >> 16);
}

__device__ __forceinline__ float tanh_fast(float x) {
    float e = __expf(2.0f * x);
    return 1.0f - 2.0f / (1.0f + e);
}

// ---- Precompute W1 fragments (bf16), order [jt][kc][lane][8]; zero accumulators ----
// MFMA A operand: A[row=j][k]; per lane: j = jt*16 + (lane&15), k = kc*32 + (lane>>4)*8 + e.
__global__ __launch_bounds__(256) void k_prep_b(const float* __restrict__ W1,
                                                float* __restrict__ ws) {
    int tg = blockIdx.x * 256 + threadIdx.x;
    if (tg < NSTRIPE * NCOPY + 1) ws[WS_ACC + tg] = 0.f;   // stripes + ticket
    if (tg >= NBFRAG) return;
    int lane = tg & 63;
    int kc = (tg >> 6) % NKC;
    int jt = tg / (NKC * 64);
    int g = lane >> 4, r = lane & 15;
    int j = jt * 16 + r;
    unsigned short v[8];
    #pragma unroll
    for (int e = 0; e < 8; e++) {
        int kglob = kc * 32 + g * 8 + e;
        int half = (kglob >= KHALF) ? 1 : 0;
        int koff = kglob - half * KHALF;
        float x = 0.f;
        if (j < HDIM && koff < HDIM) x = W1[j * 200 + half * HDIM + koff];
        v[e] = f2bf(x);
    }
    uint4 d;
    d.x = (unsigned)v[0] | ((unsigned)v[1] << 16);
    d.y = (unsigned)v[2] | ((unsigned)v[3] << 16);
    d.z = (unsigned)v[4] | ((unsigned)v[5] << 16);
    d.w = (unsigned)v[6] | ((unsigned)v[7] << 16);
    ((uint4*)(ws + WS_B))[tg] = d;
}

__device__ __forceinline__ float4 ld4c(const float* p, bool ok) {
    float4 z = make_float4(0.f, 0.f, 0.f, 0.f);
    return ok ? *(const float4*)p : z;
}

// |a - b| packed to bf16; abs folds into the cvt input modifier (VOP3) — no v_and
__device__ __forceinline__ uint4 pack_absdiff_u(float4 a0, float4 a1,
                                                float4 b0, float4 b1) {
    union { __hip_bfloat16 h[8]; uint4 u; } u;
    u.h[0] = __float2bfloat16(fabsf(a0.x - b0.x));
    u.h[1] = __float2bfloat16(fabsf(a0.y - b0.y));
    u.h[2] = __float2bfloat16(fabsf(a0.z - b0.z));
    u.h[3] = __float2bfloat16(fabsf(a0.w - b0.w));
    u.h[4] = __float2bfloat16(fabsf(a1.x - b1.x));
    u.h[5] = __float2bfloat16(fabsf(a1.y - b1.y));
    u.h[6] = __float2bfloat16(fabsf(a1.z - b1.z));
    u.h[7] = __float2bfloat16(fabsf(a1.w - b1.w));
    return u.u;
}

__device__ __forceinline__ float4 shfl32_f4(float4 v) {
    float4 r;
    r.x = __shfl_xor(v.x, 32); r.y = __shfl_xor(v.y, 32);
    r.z = __shfl_xor(v.z, 32); r.w = __shfl_xor(v.w, 32);
    return r;
}

// DPP row-rotate add (VALU pipe): x + rotate_within_16(x, N)
template<int CTRL>
__device__ __forceinline__ float dpp_radd(float x) {
    int y = __builtin_amdgcn_update_dpp(0, __builtin_bit_cast(int, x),
                                        CTRL, 0xF, 0xF, true);
    return x + __builtin_bit_cast(float, y);
}
__device__ __forceinline__ float row_reduce16(float x) {
    x = dpp_radd<0x121>(x);   // row_ror:1
    x = dpp_radd<0x122>(x);   // row_ror:2
    x = dpp_radd<0x124>(x);   // row_ror:4
    x = dpp_radd<0x128>(x);   // row_ror:8
    return x;                 // all 16 lanes of the row hold the row-sum
}

__device__ __forceinline__ float agent_load(const float* p) {
    return __hip_atomic_load(p, __ATOMIC_RELAXED, __HIP_MEMORY_SCOPE_AGENT);
}

// R23 body (best: 75.0 us — abs-at-pack, fp32-f pooling, ping-pong TPB=4,
// sched_barrier fences) + FUSED FINAL: after the stripe flush, a global ticket
// identifies the LAST block to drain; that block reads the 4 stripes with
// agent-scope atomic loads (cross-XCD L1-safe) and runs the 300->100 gated-GEMV
// epilogue itself — kills the k_final launch + full pipeline drain.
__global__ __launch_bounds__(NTHREADS, 2) void k_logits(
        const float* __restrict__ fe,
        const float* __restrict__ oc,
        const float* __restrict__ mvec,
        const float* __restrict__ b1,
        const float* __restrict__ W2,
        const float* __restrict__ W3,
        const float* __restrict__ b3,
        float* __restrict__ out,
        float* __restrict__ ws) {
    __shared__ __align__(16) uint4 Bs[NBFRAG];         // 50176 B (W1 table)
    __shared__ float poolS[KHALF];                     // 448 B block accumulator
    __shared__ float cpad[2 * KHALF];                  // oc | m, zero-padded
    __shared__ float bw[2 * KHALF];                    // b1 | W2, zero-padded
    __shared__ float sS;
    __shared__ unsigned lastFlag;

    int t = threadIdx.x;
    int w = t >> 6, lane = t & 63, g = lane >> 4, r = lane & 15;
    bool ghi = (lane & 32) != 0;     // g >= 2

    if (t == 0) sS = 0.f;
    if (t < KHALF) poolS[t] = 0.f;

    // ---- stage zero-padded params to LDS (one-time, coalesced) ----
    if (t < 2 * KHALF) {
        int half = t / KHALF, k = t % KHALF;
        cpad[t] = (k < HDIM) ? (half ? mvec[k] : oc[k]) : 0.f;
        bw[t]   = (k < HDIM) ? (half ? W2[k]   : b1[k]) : 0.f;
    }

    // ---- async stage W1 table: global -> LDS, width 16, linear (ONCE per block) ----
    {
        const uint4* Bg = (const uint4*)(ws + WS_B);
        #pragma unroll
        for (int i = 0; i < 7; i++) {
            int base = i * 512 + w * 64;          // wave-uniform
            if (base < NBFRAG) {
                __builtin_amdgcn_global_load_lds(
                    (const __attribute__((address_space(1))) unsigned int*)(Bg + base + lane),
                    (__attribute__((address_space(3))) unsigned int*)(Bs + base),
                    16, 0, 0);
            }
        }
    }

    int row_off = w * 16 + r;

    // loader: 8 float4 loads for one tile into (f0,f1); remapped cols
    auto issue_load = [&](int tile, float4* f0, float4* f1) {
        const float* fp = fe + ((long)tile * FPB + row_off) * HDIM;
        if (tile != NBLK_T - 1) {
            #pragma unroll
            for (int kc = 0; kc < 4; kc++) {
                int pk = kc * 32 + g * 8;
                int col = (pk >= KHALF) ? (pk - KHALF) : pk;
                f0[kc] = *(const float4*)(fp + col);      // may read into next row:
                f1[kc] = *(const float4*)(fp + col + 4);  // finite; killed by W1=0
            }
        } else {
            #pragma unroll
            for (int kc = 0; kc < 4; kc++) {
                int pk = kc * 32 + g * 8;
                int col = (pk >= KHALF) ? (pk - KHALF) : pk;
                f0[kc] = ld4c(fp + col, col < HDIM);
                f1[kc] = ld4c(fp + col + 4, col + 4 < HDIM);
            }
        }
    };

    float sacc = 0.f;

    // tile body: z-build (abs at pack) -> GEMM -> epilogue -> pooling from fp32 f
    auto process = [&](float4* f0c, float4* f1c) {
        uint4 zabs[NKC];
        #pragma unroll
        for (int kc = 0; kc < 4; kc++) {
            int pk = kc * 32 + g * 8;
            float4 s0 = *(const float4*)(cpad + pk);
            float4 s1 = *(const float4*)(cpad + pk + 4);
            zabs[kc] = pack_absdiff_u(f0c[kc], f1c[kc], s0, s1);
        }
        #pragma unroll
        for (int c = 0; c < 3; c++) {
            int pk = (4 + c) * 32 + g * 8;        // m cols 16+32c+8g
            float4 sa0 = ghi ? f0c[c] : f0c[c + 1];
            float4 sa1 = ghi ? f1c[c] : f1c[c + 1];
            float4 ra0 = shfl32_f4(sa0);
            float4 ra1 = shfl32_f4(sa1);
            float4 s0 = *(const float4*)(cpad + pk);
            float4 s1 = *(const float4*)(cpad + pk + 4);
            zabs[4 + c] = pack_absdiff_u(ra0, ra1, s0, s1);
        }

        float gacc = 0.f;
        #pragma unroll
        for (int jt = 0; jt < NJT; jt++) {
            int jb = jt * 16 + g * 4;
            float4 b1q = *(const float4*)(bw + jb);
            float4 w2q = *(const float4*)(bw + KHALF + jb);
            f32x4 acc = {b1q.x, b1q.y, b1q.z, b1q.w};
            #pragma unroll
            for (int kc = 0; kc < NKC; kc++) {
                short8 av = __builtin_bit_cast(short8, Bs[(jt * NKC + kc) * 64 + lane]);
                acc = __builtin_amdgcn_mfma_f32_16x16x32_bf16(
                    av, __builtin_bit_cast(short8, zabs[kc]), acc, 0, 0, 0);
            }
            gacc = fmaf(tanh_fast(acc[0]), w2q.x, gacc);
            gacc = fmaf(tanh_fast(acc[1]), w2q.y, gacc);
            gacc = fmaf(tanh_fast(acc[2]), w2q.z, gacc);
            gacc = fmaf(tanh_fast(acc[3]), w2q.w, gacc);
        }
        gacc += __shfl_xor(gacc, 16);
        gacc += __shfl_xor(gacc, 32);
        float w_r = __expf(gacc);   // b2 dropped (softmax-invariant); |logit| <~ 8
        sacc += w_r;

        // pooling: p = w_r * f (fp32, straight from live regs), DPP reduce, LDS add
        float p[4][8];
        #pragma unroll
        for (int c = 0; c < 4; c++) {
            p[c][0] = w_r * f0c[c].x; p[c][1] = w_r * f0c[c].y;
            p[c][2] = w_r * f0c[c].z; p[c][3] = w_r * f0c[c].w;
            p[c][4] = w_r * f1c[c].x; p[c][5] = w_r * f1c[c].y;
            p[c][6] = w_r * f1c[c].z; p[c][7] = w_r * f1c[c].w;
        }
        #pragma unroll
        for (int c = 0; c < 4; c++)
            #pragma unroll
            for (int e = 0; e < 8; e++) p[c][e] = row_reduce16(p[c][e]);
        if (r == 0) {
            #pragma unroll
            for (int c = 0; c < 4; c++) {
                int pk = c * 32 + g * 8;
                if (pk < KHALF) {
                    #pragma unroll
                    for (int e = 0; e < 8; e++)
                        atomicAdd(&poolS[pk + e], p[c][e]);
                }
            }
        }
    };

    int tile0 = blockIdx.x * TPB;
    float4 fA0[4], fA1[4], fB0[4], fB1[4];

    issue_load(tile0 + 0, fA0, fA1);
    __syncthreads();                      // Bs/cpad/bw/poolS ready (drains vmcnt too)

    issue_load(tile0 + 1, fB0, fB1);      // prefetch t1 under t0's compute
    process(fA0, fA1);
    __builtin_amdgcn_sched_barrier(0);

    issue_load(tile0 + 2, fA0, fA1);      // prefetch t2 under t1's compute
    process(fB0, fB1);
    __builtin_amdgcn_sched_barrier(0);

    issue_load(tile0 + 3, fB0, fB1);      // prefetch t3 under t2's compute
    process(fA0, fA1);
    __builtin_amdgcn_sched_barrier(0);

    process(fB0, fB1);

    // ---- end-of-block: denom partial + flush ----
    float s16 = row_reduce16(sacc);   // w_r duplicated across g; take one copy
    if (lane == 0) atomicAdd(&sS, s16);
    __syncthreads();

    int cp = (blockIdx.x & (NSTRIPE - 1)) * NCOPY;
    if (t < KHALF && t < HDIM) atomicAdd(&ws[WS_ACC + cp + t], poolS[t]);
    if (t == 0) atomicAdd(&ws[WS_ACC + cp + KHALF], sS);

    // ---- last-block fused final ----
    __threadfence();                  // flush atomics visible device-wide
    if (t == 0) {
        unsigned old = atomicAdd((unsigned*)(ws + WS_TICKET), 1u);
        lastFlag = (old == GRID - 1) ? 1u : 0u;
    }
    __syncthreads();
    if (!lastFlag) return;

    // this block drained last: all stripes complete. Reuse Bs LDS as scratch.
    float* vv   = (float*)Bs;         // [300]
    float* part = (float*)Bs + 512;   // [5][100]
    __shared__ float Sval;

    if (t == 0) {
        float S = 0.f;
        #pragma unroll
        for (int i = 0; i < NSTRIPE; i++)
            S += agent_load(&ws[WS_ACC + i * NCOPY + KHALF]);
        Sval = S;
    }
    if (t < HDIM) {
        float corr = 0.f;
        #pragma unroll
        for (int i = 0; i < NSTRIPE; i++)
            corr += agent_load(&ws[WS_ACC + i * NCOPY + t]);
        vv[HDIM + t] = corr;          // scaled by 1/S after Sval ready
        vv[t] = mvec[t];
        vv[2 * HDIM + t] = oc[t];
    }
    __syncthreads();
    if (t < HDIM) vv[HDIM + t] = vv[HDIM + t] / Sval;   // pool is sum(w*f) directly
    __syncthreads();

    // 300->100 gated GEMV: 5 slices x 100 outputs x 60 k each
    if (t < 500) {
        int sl = t / HDIM, h = t % HDIM;
        const float* wr = W3 + h * 3 * HDIM + sl * 60;
        const float* vp = vv + sl * 60;
        float a = 0.f;
        #pragma unroll 4
        for (int k = 0; k < 60; k++) a = fmaf(wr[k], vp[k], a);
        part[sl * HDIM + h] = a;
    }
    __syncthreads();
    if (t < HDIM) {
        float a = b3[t];
        #pragma unroll
        for (int sl = 0; sl < 5; sl++) a += part[sl * HDIM + t];
        out[t] = fmaxf(a, 0.f);
    }
}

extern "C" void kernel_launch(void* const* d_in, const int* in_sizes, int n_in,
                              void* d_out, int out_size, void* d_ws, size_t ws_size,
                              hipStream_t stream) {
    const float* mvec = (const float*)d_in[0];
    const float* oh   = (const float*)d_in[1];
    const float* fe   = (const float*)d_in[2];
    const float* W1   = (const float*)d_in[3];
    const float* b1   = (const float*)d_in[4];
    const float* W2   = (const float*)d_in[5];
    const float* W3   = (const float*)d_in[7];
    const float* b3   = (const float*)d_in[8];
    float* ws  = (float*)d_ws;
    float* out = (float*)d_out;

    k_prep_b<<<13, 256, 0, stream>>>(W1, ws);
    k_logits<<<GRID, NTHREADS, 0, stream>>>(fe, oh, mvec, b1, W2, W3, b3, out, ws);
}

// Round 26
// 74.771 us; speedup vs baseline: 1.5683x; 1.5683x over previous
//
#include <hip/hip_runtime.h>
#include <hip/hip_bf16.h>
#include <math.h>

#define HDIM 100
#define NFACT 262144
#define FPB   128             // facts per tile (8 waves x 16)
#define NBLK_T 2048           // tiles total
#define TPB   4               // tiles per block (manually unrolled, ping-pong)
#define GRID  (NBLK_T / TPB)  // 512 blocks
#define NTHREADS 512

// K packed to 224: k in [0,112) -> |f - oc| (valid k<100), k in [112,224) -> |f - m|
// (valid k-112<100). Dead k ranges have W1-frag == 0 and z == 0. 112 % 8 == 0 so no
// 8-element MFMA k-group straddles the boundary.
#define KHALF 112
#define NJT 7                 // j-tiles of 16 (112 >= 100)
#define NKC 7                 // k-chunks of 32 (224)
#define NBFRAG (NJT * NKC * 64)   // 3136 uint4 = 50176 B

#define NCOPY 116             // accumulator stripe: pool[112] + S at [112]
#define NSTRIPE 4             // 32 stripes thrashed L2 lines (R12: 49 MB writes)

using short8 = __attribute__((ext_vector_type(8))) short;
using f32x4  = __attribute__((ext_vector_type(4))) float;

// ---------------- ws float-offset layout ----------------
#define WS_B    0                 // 12544 floats (3136 uint4 W1-fragments, bf16 bits)
#define WS_ACC  12544             // NSTRIPE stripes x 116 floats (zeroed by k_prep_b)

__device__ __forceinline__ unsigned short f2bf(float x) {
    unsigned u = __builtin_bit_cast(unsigned, x);
    u += 0x7FFFu + ((u >> 16) & 1u);          // RNE round to bf16
    return (unsigned short)(u >> 16);
}

__device__ __forceinline__ float tanh_fast(float x) {
    float e = __expf(2.0f * x);
    return 1.0f - 2.0f / (1.0f + e);
}

// ---- Precompute W1 fragments (bf16), order [jt][kc][lane][8]; zero accumulators ----
// MFMA A operand: A[row=j][k]; per lane: j = jt*16 + (lane&15), k = kc*32 + (lane>>4)*8 + e.
__global__ __launch_bounds__(256) void k_prep_b(const float* __restrict__ W1,
                                                float* __restrict__ ws) {
    int tg = blockIdx.x * 256 + threadIdx.x;
    if (tg < NSTRIPE * NCOPY) ws[WS_ACC + tg] = 0.f;   // zero all stripes each call
    if (tg >= NBFRAG) return;
    int lane = tg & 63;
    int kc = (tg >> 6) % NKC;
    int jt = tg / (NKC * 64);
    int g = lane >> 4, r = lane & 15;
    int j = jt * 16 + r;
    unsigned short v[8];
    #pragma unroll
    for (int e = 0; e < 8; e++) {
        int kglob = kc * 32 + g * 8 + e;
        int half = (kglob >= KHALF) ? 1 : 0;
        int koff = kglob - half * KHALF;
        float x = 0.f;
        if (j < HDIM && koff < HDIM) x = W1[j * 200 + half * HDIM + koff];
        v[e] = f2bf(x);
    }
    uint4 d;
    d.x = (unsigned)v[0] | ((unsigned)v[1] << 16);
    d.y = (unsigned)v[2] | ((unsigned)v[3] << 16);
    d.z = (unsigned)v[4] | ((unsigned)v[5] << 16);
    d.w = (unsigned)v[6] | ((unsigned)v[7] << 16);
    ((uint4*)(ws + WS_B))[tg] = d;
}

__device__ __forceinline__ float4 ld4c(const float* p, bool ok) {
    float4 z = make_float4(0.f, 0.f, 0.f, 0.f);
    return ok ? *(const float4*)p : z;
}

// |a - b| packed to bf16; abs folds into the cvt input modifier (VOP3) — no v_and
__device__ __forceinline__ uint4 pack_absdiff_u(float4 a0, float4 a1,
                                                float4 b0, float4 b1) {
    union { __hip_bfloat16 h[8]; uint4 u; } u;
    u.h[0] = __float2bfloat16(fabsf(a0.x - b0.x));
    u.h[1] = __float2bfloat16(fabsf(a0.y - b0.y));
    u.h[2] = __float2bfloat16(fabsf(a0.z - b0.z));
    u.h[3] = __float2bfloat16(fabsf(a0.w - b0.w));
    u.h[4] = __float2bfloat16(fabsf(a1.x - b1.x));
    u.h[5] = __float2bfloat16(fabsf(a1.y - b1.y));
    u.h[6] = __float2bfloat16(fabsf(a1.z - b1.z));
    u.h[7] = __float2bfloat16(fabsf(a1.w - b1.w));
    return u.u;
}

__device__ __forceinline__ float4 shfl32_f4(float4 v) {
    float4 r;
    r.x = __shfl_xor(v.x, 32); r.y = __shfl_xor(v.y, 32);
    r.z = __shfl_xor(v.z, 32); r.w = __shfl_xor(v.w, 32);
    return r;
}

// DPP row-rotate add (VALU pipe): x + rotate_within_16(x, N)
template<int CTRL>
__device__ __forceinline__ float dpp_radd(float x) {
    int y = __builtin_amdgcn_update_dpp(0, __builtin_bit_cast(int, x),
                                        CTRL, 0xF, 0xF, true);
    return x + __builtin_bit_cast(float, y);
}
__device__ __forceinline__ float row_reduce16(float x) {
    x = dpp_radd<0x121>(x);   // row_ror:1
    x = dpp_radd<0x122>(x);   // row_ror:2
    x = dpp_radd<0x124>(x);   // row_ror:4
    x = dpp_radd<0x128>(x);   // row_ror:8
    return x;                 // all 16 lanes of the row hold the row-sum
}

// R23 configuration — the measured optimum across R17-R25's structural sweep:
// abs folded at pack (no and_mask in GEMM), pooling = sum w*f from live fp32
// regs, ping-pong prefetch TPB=4, sched_barrier(0) fences (anti-spill), 4-stripe
// accumulator, separate tiny k_final (fusing it regressed 2x: per-block
// __threadfence L2 drain, R25).
__global__ __launch_bounds__(NTHREADS, 2) void k_logits(
        const float* __restrict__ fe,
        const float* __restrict__ oc,
        const float* __restrict__ mvec,
        const float* __restrict__ b1,
        const float* __restrict__ W2,
        float* __restrict__ ws) {
    __shared__ __align__(16) uint4 Bs[NBFRAG];         // 50176 B (W1 table)
    __shared__ float poolS[KHALF];                     // 448 B block accumulator
    __shared__ float cpad[2 * KHALF];                  // oc | m, zero-padded
    __shared__ float bw[2 * KHALF];                    // b1 | W2, zero-padded
    __shared__ float sS;

    int t = threadIdx.x;
    int w = t >> 6, lane = t & 63, g = lane >> 4, r = lane & 15;
    bool ghi = (lane & 32) != 0;     // g >= 2

    if (t == 0) sS = 0.f;
    if (t < KHALF) poolS[t] = 0.f;

    // ---- stage zero-padded params to LDS (one-time, coalesced) ----
    if (t < 2 * KHALF) {
        int half = t / KHALF, k = t % KHALF;
        cpad[t] = (k < HDIM) ? (half ? mvec[k] : oc[k]) : 0.f;
        bw[t]   = (k < HDIM) ? (half ? W2[k]   : b1[k]) : 0.f;
    }

    // ---- async stage W1 table: global -> LDS, width 16, linear (ONCE per block) ----
    {
        const uint4* Bg = (const uint4*)(ws + WS_B);
        #pragma unroll
        for (int i = 0; i < 7; i++) {
            int base = i * 512 + w * 64;          // wave-uniform
            if (base < NBFRAG) {
                __builtin_amdgcn_global_load_lds(
                    (const __attribute__((address_space(1))) unsigned int*)(Bg + base + lane),
                    (__attribute__((address_space(3))) unsigned int*)(Bs + base),
                    16, 0, 0);
            }
        }
    }

    int row_off = w * 16 + r;

    // loader: 8 float4 loads for one tile into (f0,f1); remapped cols
    auto issue_load = [&](int tile, float4* f0, float4* f1) {
        const float* fp = fe + ((long)tile * FPB + row_off) * HDIM;
        if (tile != NBLK_T - 1) {
            #pragma unroll
            for (int kc = 0; kc < 4; kc++) {
                int pk = kc * 32 + g * 8;
                int col = (pk >= KHALF) ? (pk - KHALF) : pk;
                f0[kc] = *(const float4*)(fp + col);      // may read into next row:
                f1[kc] = *(const float4*)(fp + col + 4);  // finite; killed by W1=0
            }
        } else {
            #pragma unroll
            for (int kc = 0; kc < 4; kc++) {
                int pk = kc * 32 + g * 8;
                int col = (pk >= KHALF) ? (pk - KHALF) : pk;
                f0[kc] = ld4c(fp + col, col < HDIM);
                f1[kc] = ld4c(fp + col + 4, col + 4 < HDIM);
            }
        }
    };

    float sacc = 0.f;

    // tile body: z-build (abs at pack) -> GEMM -> epilogue -> pooling from fp32 f
    auto process = [&](float4* f0c, float4* f1c) {
        // all-abs z fragments; kc=3 g>=2 covers m cols 0..15 via the load remap
        uint4 zabs[NKC];
        #pragma unroll
        for (int kc = 0; kc < 4; kc++) {
            int pk = kc * 32 + g * 8;
            float4 s0 = *(const float4*)(cpad + pk);
            float4 s1 = *(const float4*)(cpad + pk + 4);
            zabs[kc] = pack_absdiff_u(f0c[kc], f1c[kc], s0, s1);
        }
        // m-half via g^2 exchange: receiver needs owner block c+(g>=2)
        #pragma unroll
        for (int c = 0; c < 3; c++) {
            int pk = (4 + c) * 32 + g * 8;        // m cols 16+32c+8g
            float4 sa0 = ghi ? f0c[c] : f0c[c + 1];
            float4 sa1 = ghi ? f1c[c] : f1c[c + 1];
            float4 ra0 = shfl32_f4(sa0);
            float4 ra1 = shfl32_f4(sa1);
            float4 s0 = *(const float4*)(cpad + pk);
            float4 s1 = *(const float4*)(cpad + pk + 4);
            zabs[4 + c] = pack_absdiff_u(ra0, ra1, s0, s1);
        }

        // GEMM: C[j][fact] = mfma(W1frag, |z|); C col = r = my fact; b1 in C-init
        float gacc = 0.f;
        #pragma unroll
        for (int jt = 0; jt < NJT; jt++) {
            int jb = jt * 16 + g * 4;
            float4 b1q = *(const float4*)(bw + jb);
            float4 w2q = *(const float4*)(bw + KHALF + jb);
            f32x4 acc = {b1q.x, b1q.y, b1q.z, b1q.w};
            #pragma unroll
            for (int kc = 0; kc < NKC; kc++) {
                short8 av = __builtin_bit_cast(short8, Bs[(jt * NKC + kc) * 64 + lane]);
                acc = __builtin_amdgcn_mfma_f32_16x16x32_bf16(
                    av, __builtin_bit_cast(short8, zabs[kc]), acc, 0, 0, 0);
            }
            gacc = fmaf(tanh_fast(acc[0]), w2q.x, gacc);
            gacc = fmaf(tanh_fast(acc[1]), w2q.y, gacc);
            gacc = fmaf(tanh_fast(acc[2]), w2q.z, gacc);
            gacc = fmaf(tanh_fast(acc[3]), w2q.w, gacc);
        }
        gacc += __shfl_xor(gacc, 16);
        gacc += __shfl_xor(gacc, 32);
        float w_r = __expf(gacc);   // b2 dropped (softmax-invariant); |logit| <~ 8
        sacc += w_r;

        // pooling: p = w_r * f (fp32, straight from live regs), DPP reduce, LDS add
        float p[4][8];
        #pragma unroll
        for (int c = 0; c < 4; c++) {
            p[c][0] = w_r * f0c[c].x; p[c][1] = w_r * f0c[c].y;
            p[c][2] = w_r * f0c[c].z; p[c][3] = w_r * f0c[c].w;
            p[c][4] = w_r * f1c[c].x; p[c][5] = w_r * f1c[c].y;
            p[c][6] = w_r * f1c[c].z; p[c][7] = w_r * f1c[c].w;
        }
        #pragma unroll
        for (int c = 0; c < 4; c++)
            #pragma unroll
            for (int e = 0; e < 8; e++) p[c][e] = row_reduce16(p[c][e]);
        if (r == 0) {      // lanes g=0..3; slots pk=c*32+g*8 (+e), valid when pk<112
            #pragma unroll
            for (int c = 0; c < 4; c++) {
                int pk = c * 32 + g * 8;
                if (pk < KHALF) {
                    #pragma unroll
                    for (int e = 0; e < 8; e++)
                        atomicAdd(&poolS[pk + e], p[c][e]);
                }
            }
        }
    };

    int tile0 = blockIdx.x * TPB;
    float4 fA0[4], fA1[4], fB0[4], fB1[4];

    issue_load(tile0 + 0, fA0, fA1);
    __syncthreads();                      // Bs/cpad/bw/poolS ready (drains vmcnt too)

    issue_load(tile0 + 1, fB0, fB1);      // prefetch t1 under t0's compute
    process(fA0, fA1);
    __builtin_amdgcn_sched_barrier(0);

    issue_load(tile0 + 2, fA0, fA1);      // prefetch t2 under t1's compute
    process(fB0, fB1);
    __builtin_amdgcn_sched_barrier(0);

    issue_load(tile0 + 3, fB0, fB1);      // prefetch t3 under t2's compute
    process(fA0, fA1);
    __builtin_amdgcn_sched_barrier(0);

    process(fB0, fB1);

    // ---- end-of-block: denom partial + flush ----
    float s16 = row_reduce16(sacc);   // w_r duplicated across g; take one copy
    if (lane == 0) atomicAdd(&sS, s16);
    __syncthreads();

    int cp = (blockIdx.x & (NSTRIPE - 1)) * NCOPY;
    if (t < KHALF && t < HDIM) atomicAdd(&ws[WS_ACC + cp + t], poolS[t]);
    if (t == 0) atomicAdd(&ws[WS_ACC + cp + KHALF], sS);
}

// Tiny epilogue: c = pool/S (exact weighted mean of f); gated update. One block.
__global__ __launch_bounds__(128) void k_final(
        const float* __restrict__ mvec,
        const float* __restrict__ oc,
        const float* __restrict__ W3,
        const float* __restrict__ b3,
        const float* __restrict__ ws,
        float* __restrict__ out) {
    __shared__ float vv[300];
    int t = threadIdx.x;
    float S = 0.f;
    #pragma unroll
    for (int i = 0; i < NSTRIPE; i++) S += ws[WS_ACC + i * NCOPY + KHALF];
    if (t < HDIM) {
        float corr = 0.f;
        #pragma unroll
        for (int i = 0; i < NSTRIPE; i++) corr += ws[WS_ACC + i * NCOPY + t];
        vv[t] = mvec[t];
        vv[HDIM + t] = corr / S;          // pooling is sum(w*f) directly
        vv[2 * HDIM + t] = oc[t];
    }
    __syncthreads();
    if (t < HDIM) {
        float a = b3[t];
        const float* wr = W3 + t * 3 * HDIM;
        #pragma unroll 4
        for (int k = 0; k < 3 * HDIM; k++) a = fmaf(wr[k], vv[k], a);
        out[t] = fmaxf(a, 0.f);
    }
}

extern "C" void kernel_launch(void* const* d_in, const int* in_sizes, int n_in,
                              void* d_out, int out_size, void* d_ws, size_t ws_size,
                              hipStream_t stream) {
    const float* mvec = (const float*)d_in[0];
    const float* oh   = (const float*)d_in[1];
    const float* fe   = (const float*)d_in[2];
    const float* W1   = (const float*)d_in[3];
    const float* b1   = (const float*)d_in[4];
    const float* W2   = (const float*)d_in[5];
    const float* W3   = (const float*)d_in[7];
    const float* b3   = (const float*)d_in[8];
    float* ws  = (float*)d_ws;
    float* out = (float*)d_out;

    k_prep_b<<<13, 256, 0, stream>>>(W1, ws);
    k_logits<<<GRID, NTHREADS, 0, stream>>>(fe, oh, mvec, b1, W2, ws);
    k_final<<<1, 128, 0, stream>>>(mvec, oh, W3, b3, ws, out);
}